// Round 1
// baseline (112.469 us; speedup 1.0000x reference)
//
#include <hip/hip_runtime.h>
#include <hip/hip_bf16.h>

// Problem constants (from reference)
#define BATCH   8192
#define NGRP    8
#define MAXGS   64
#define DMODEL  2048
#define TILES   512   // worst-case 16-row tiles per group (BATCH/16)

typedef __attribute__((ext_vector_type(8))) short  short8;
typedef __attribute__((ext_vector_type(4))) float  f32x4;

// ws layout:
//   [0, 32)                      int cnt[8]
//   [1024, 1024 + 8*8192*4)      int lists[8][8192]
//   [W_OFF, W_OFF + 1M*2)        ushort Wb[8][64][2048]  (bf16)
#define LISTS_OFF 1024
#define W_OFF (LISTS_OFF + NGRP * BATCH * 4)

static __device__ __forceinline__ unsigned short f2bf(float f) {
    // round-to-nearest-even f32 -> bf16 (inputs are finite randoms; no NaN path needed)
    unsigned u = __float_as_uint(f);
    u += 0x7FFFu + ((u >> 16) & 1u);
    return (unsigned short)(u >> 16);
}

// Phase 0: zero group counters + convert W (f32 -> bf16) into ws.
// grid: 1024 x 256 threads, 4 elems/thread = 1,048,576 elems exactly.
__global__ __launch_bounds__(256) void init_kernel(const float* __restrict__ W,
                                                   unsigned short* __restrict__ Wb,
                                                   int* __restrict__ cnt) {
    int idx = blockIdx.x * 256 + threadIdx.x;
    if (idx < NGRP) cnt[idx] = 0;
    int e = idx * 4;
    float4 w = *reinterpret_cast<const float4*>(W + e);
    ushort4 o;
    o.x = f2bf(w.x); o.y = f2bf(w.y); o.z = f2bf(w.z); o.w = f2bf(w.w);
    *reinterpret_cast<ushort4*>(Wb + e) = o;
}

// Phase 1: bucket samples by chosen group. Ballot-aggregated atomics:
// one atomicAdd per (wave, group) = at most 8 per wave.
// List order is nondeterministic but output VALUES are order-independent.
__global__ __launch_bounds__(256) void bucket_kernel(const int* __restrict__ chosen,
                                                     int* __restrict__ cnt,
                                                     int* __restrict__ lists) {
    int b = blockIdx.x * 256 + threadIdx.x;   // BATCH == 32*256 exactly
    int g = chosen[b];
    int lane = threadIdx.x & 63;
    int pos = 0;
    #pragma unroll
    for (int gg = 0; gg < NGRP; ++gg) {
        unsigned long long m = __ballot(g == gg);
        if (g == gg) {
            int leader = __ffsll((unsigned long long)m) - 1;
            int base = 0;
            if (lane == leader) base = atomicAdd(&cnt[gg], __popcll(m));
            base = __shfl(base, leader);
            pos = base + __popcll(m & ((1ull << lane) - 1ull));
        }
    }
    lists[g * BATCH + pos] = b;
}

// Phase 2: per-group GEMM. One wave (64 threads) per 16-sample x 64-out tile.
// A = gathered hidden rows (f32 -> bf16 in-reg), B = pre-converted W bf16.
// mfma_f32_16x16x32_bf16: A lane l: row=l&15, k=8*(l>>4)+j (contiguous);
// B lane l: col=l&15, same k mapping; C/D: col=l&15, row=(l>>4)*4+reg.
__global__ __launch_bounds__(64) void gemm_kernel(
    const float* __restrict__ hidden,
    const float* __restrict__ bias,
    const int* __restrict__ gsizes,
    const int* __restrict__ cnt,
    const int* __restrict__ lists,
    const unsigned short* __restrict__ Wb,
    float* __restrict__ out)
{
    int bid = blockIdx.x;
    int g = bid >> 9;              // TILES == 512
    int t = bid & (TILES - 1);
    int c = cnt[g];
    int m0 = t << 4;
    if (m0 >= c) return;           // empty tile: exit

    int lane = threadIdx.x;
    int lrow = lane & 15;
    int kg   = lane >> 4;          // 0..3

    // A: this lane's sample row (clamped for tail padding; stores suppressed below)
    int mrow  = m0 + lrow;
    int msafe = mrow < c ? mrow : c - 1;
    int sample = lists[g * BATCH + msafe];
    const float* __restrict__ hrow =
        hidden + ((size_t)sample * NGRP + g) * DMODEL + kg * 8;
    // B: W_bf16[g][n][k], n = tile*16 + lrow, 8 contiguous k per lane
    const unsigned short* __restrict__ wb =
        Wb + ((size_t)g * MAXGS + lrow) * DMODEL + kg * 8;

    f32x4 acc[4] = {f32x4{0,0,0,0}, f32x4{0,0,0,0}, f32x4{0,0,0,0}, f32x4{0,0,0,0}};

    #pragma unroll 4
    for (int k0 = 0; k0 < DMODEL; k0 += 32) {
        float4 a0 = *reinterpret_cast<const float4*>(hrow + k0);
        float4 a1 = *reinterpret_cast<const float4*>(hrow + k0 + 4);
        short8 af;
        af[0] = (short)f2bf(a0.x);
        af[1] = (short)f2bf(a0.y);
        af[2] = (short)f2bf(a0.z);
        af[3] = (short)f2bf(a0.w);
        af[4] = (short)f2bf(a1.x);
        af[5] = (short)f2bf(a1.y);
        af[6] = (short)f2bf(a1.z);
        af[7] = (short)f2bf(a1.w);
        short8 b0 = *reinterpret_cast<const short8*>(wb + k0);
        short8 b1 = *reinterpret_cast<const short8*>(wb + 16 * DMODEL + k0);
        short8 b2 = *reinterpret_cast<const short8*>(wb + 32 * DMODEL + k0);
        short8 b3 = *reinterpret_cast<const short8*>(wb + 48 * DMODEL + k0);
        acc[0] = __builtin_amdgcn_mfma_f32_16x16x32_bf16(af, b0, acc[0], 0, 0, 0);
        acc[1] = __builtin_amdgcn_mfma_f32_16x16x32_bf16(af, b1, acc[1], 0, 0, 0);
        acc[2] = __builtin_amdgcn_mfma_f32_16x16x32_bf16(af, b2, acc[2], 0, 0, 0);
        acc[3] = __builtin_amdgcn_mfma_f32_16x16x32_bf16(af, b3, acc[3], 0, 0, 0);
    }

    // Epilogue: add bias, write preds + valid mask.
    // Lane's acc element r of tile ti -> row m0 + kg*4 + r, col ti*16 + lrow.
    int gsz = gsizes[g];
    float bv[4];
    #pragma unroll
    for (int ti = 0; ti < 4; ++ti) bv[ti] = bias[g * MAXGS + ti * 16 + lrow];

    #pragma unroll
    for (int r = 0; r < 4; ++r) {
        int m = m0 + kg * 4 + r;
        if (m < c) {
            int smp = lists[g * BATCH + m];
            float* prow = out + (size_t)smp * MAXGS;
            float* vrow = out + (size_t)BATCH * MAXGS + (size_t)smp * MAXGS;
            #pragma unroll
            for (int ti = 0; ti < 4; ++ti) {
                int n = ti * 16 + lrow;
                prow[n] = acc[ti][r] + bv[ti];       // padded n: 0 + 0 == 0 exactly
                vrow[n] = (n < gsz) ? 1.0f : 0.0f;
            }
        }
    }
}

extern "C" void kernel_launch(void* const* d_in, const int* in_sizes, int n_in,
                              void* d_out, int out_size, void* d_ws, size_t ws_size,
                              hipStream_t stream) {
    const float* hidden = (const float*)d_in[0];   // [8192, 8, 2048] f32
    const int*   chosen = (const int*)d_in[1];     // [8192] i32
    const float* W      = (const float*)d_in[2];   // [8, 64, 2048] f32 (zero-padded)
    const float* bias   = (const float*)d_in[3];   // [8, 64] f32 (zero-padded)
    const int*   gs     = (const int*)d_in[4];     // [8] i32
    float* out = (float*)d_out;                    // [8192*64 preds | 8192*64 valid]

    char* ws = (char*)d_ws;
    int* cnt   = (int*)ws;
    int* lists = (int*)(ws + LISTS_OFF);
    unsigned short* Wb = (unsigned short*)(ws + W_OFF);

    init_kernel<<<dim3(1024), dim3(256), 0, stream>>>(W, Wb, cnt);
    bucket_kernel<<<dim3(32), dim3(256), 0, stream>>>(chosen, cnt, lists);
    gemm_kernel<<<dim3(NGRP * TILES), dim3(64), 0, stream>>>(
        hidden, bias, gs, cnt, lists, Wb, out);
}

// Round 2
// 58.791 us; speedup vs baseline: 1.9130x; 1.9130x over previous
//
#include <hip/hip_runtime.h>
#include <hip/hip_bf16.h>

// Problem constants (from reference)
#define BATCH   8192
#define NGRP    8
#define MAXGS   64
#define DMODEL  2048
#define TILES   512       // worst-case 16-row tiles per group (BATCH/16)
#define SPLITK  4
#define KCHUNK  (DMODEL / SPLITK)   // 512

typedef __attribute__((ext_vector_type(8))) short  short8;
typedef __attribute__((ext_vector_type(4))) float  f32x4;

// ws layout:
//   [0, 32)                      int cnt[8]
//   [1024, 1024 + 8*8192*4)      int lists[8][8192]
//   [W_OFF, W_OFF + 1M*2)        ushort Wb[8][64][2048]  (bf16)
#define LISTS_OFF 1024
#define W_OFF (LISTS_OFF + NGRP * BATCH * 4)

static __device__ __forceinline__ unsigned short f2bf(float f) {
    // round-to-nearest-even f32 -> bf16 (finite inputs; no NaN path needed)
    unsigned u = __float_as_uint(f);
    u += 0x7FFFu + ((u >> 16) & 1u);
    return (unsigned short)(u >> 16);
}

// Phase 0: zero group counters + convert W (f32 -> bf16) into ws.
__global__ __launch_bounds__(256) void init_kernel(const float* __restrict__ W,
                                                   unsigned short* __restrict__ Wb,
                                                   int* __restrict__ cnt) {
    int idx = blockIdx.x * 256 + threadIdx.x;
    if (idx < NGRP) cnt[idx] = 0;
    int e = idx * 4;
    float4 w = *reinterpret_cast<const float4*>(W + e);
    ushort4 o;
    o.x = f2bf(w.x); o.y = f2bf(w.y); o.z = f2bf(w.z); o.w = f2bf(w.w);
    *reinterpret_cast<ushort4*>(Wb + e) = o;
}

// Phase 1: bucket samples by chosen group (ballot-aggregated atomics).
// List order nondeterministic; per-sample output values are order-independent.
__global__ __launch_bounds__(256) void bucket_kernel(const int* __restrict__ chosen,
                                                     int* __restrict__ cnt,
                                                     int* __restrict__ lists) {
    int b = blockIdx.x * 256 + threadIdx.x;   // BATCH == 32*256 exactly
    int g = chosen[b];
    int lane = threadIdx.x & 63;
    int pos = 0;
    #pragma unroll
    for (int gg = 0; gg < NGRP; ++gg) {
        unsigned long long m = __ballot(g == gg);
        if (g == gg) {
            int leader = __ffsll((unsigned long long)m) - 1;
            int base = 0;
            if (lane == leader) base = atomicAdd(&cnt[gg], __popcll(m));
            base = __shfl(base, leader);
            pos = base + __popcll(m & ((1ull << lane) - 1ull));
        }
    }
    lists[g * BATCH + pos] = b;
}

// Phase 2: per-group GEMM, split-K=4 inside a 4-wave block.
// bid mapping g = bid&7 spreads ACTIVE tiles (t < cnt/16) across all CUs/XCDs
// (previous g*512+t mapping aliased all live blocks onto 1/4 of the CUs).
// Wave w computes K-chunk [w*512, w*512+512) of the 16x64 tile; LDS-reduce.
// mfma_f32_16x16x32_bf16: A lane l: row=l&15, contiguous k per 16-lane group;
// C/D: col=l&15, row=(l>>4)*4+reg.
__global__ __launch_bounds__(256, 2) void gemm_kernel(
    const float* __restrict__ hidden,
    const float* __restrict__ bias,
    const int* __restrict__ gsizes,
    const int* __restrict__ cnt,
    const int* __restrict__ lists,
    const unsigned short* __restrict__ Wb,
    float* __restrict__ out)
{
    int bid = blockIdx.x;
    int g = bid & (NGRP - 1);
    int t = bid >> 3;
    int c = cnt[g];
    int m0 = t << 4;
    if (m0 >= c) return;           // empty tile: whole block exits (uniform)

    int tid  = threadIdx.x;
    int w    = tid >> 6;           // wave id 0..3 -> K chunk
    int lane = tid & 63;
    int lrow = lane & 15;
    int kg   = lane >> 4;          // 0..3

    __shared__ float red[SPLITK][64][17];   // +1 pad: conflict-light

    // A: this lane's sample row (clamped for tail; stores suppressed below)
    int mrow  = m0 + lrow;
    int msafe = mrow < c ? mrow : c - 1;
    int sample = lists[g * BATCH + msafe];
    const float* __restrict__ hrow =
        hidden + ((size_t)sample * NGRP + g) * DMODEL + w * KCHUNK + kg * 8;
    const unsigned short* __restrict__ wb =
        Wb + ((size_t)g * MAXGS + lrow) * DMODEL + w * KCHUNK + kg * 8;

    f32x4 acc[4] = {f32x4{0,0,0,0}, f32x4{0,0,0,0}, f32x4{0,0,0,0}, f32x4{0,0,0,0}};

    #pragma unroll 4
    for (int k0 = 0; k0 < KCHUNK; k0 += 32) {
        float4 a0 = *reinterpret_cast<const float4*>(hrow + k0);
        float4 a1 = *reinterpret_cast<const float4*>(hrow + k0 + 4);
        short8 af;
        af[0] = (short)f2bf(a0.x);
        af[1] = (short)f2bf(a0.y);
        af[2] = (short)f2bf(a0.z);
        af[3] = (short)f2bf(a0.w);
        af[4] = (short)f2bf(a1.x);
        af[5] = (short)f2bf(a1.y);
        af[6] = (short)f2bf(a1.z);
        af[7] = (short)f2bf(a1.w);
        short8 b0 = *reinterpret_cast<const short8*>(wb + k0);
        short8 b1 = *reinterpret_cast<const short8*>(wb + 16 * DMODEL + k0);
        short8 b2 = *reinterpret_cast<const short8*>(wb + 32 * DMODEL + k0);
        short8 b3 = *reinterpret_cast<const short8*>(wb + 48 * DMODEL + k0);
        acc[0] = __builtin_amdgcn_mfma_f32_16x16x32_bf16(af, b0, acc[0], 0, 0, 0);
        acc[1] = __builtin_amdgcn_mfma_f32_16x16x32_bf16(af, b1, acc[1], 0, 0, 0);
        acc[2] = __builtin_amdgcn_mfma_f32_16x16x32_bf16(af, b2, acc[2], 0, 0, 0);
        acc[3] = __builtin_amdgcn_mfma_f32_16x16x32_bf16(af, b3, acc[3], 0, 0, 0);
    }

    // Stash partials: red[w][lane][ti*4+r]
    #pragma unroll
    for (int ti = 0; ti < 4; ++ti)
        #pragma unroll
        for (int r = 0; r < 4; ++r)
            red[w][lane][ti * 4 + r] = acc[ti][r];

    __syncthreads();

    // Reduce over the 4 K-chunks + bias + store. 4 outputs per thread.
    int gsz = gsizes[g];
    #pragma unroll
    for (int i = 0; i < 4; ++i) {
        int o  = tid + i * 256;        // 0..1023 = (m_local, n)
        int ml = o >> 6;
        int n  = o & 63;
        int rl = ((ml >> 2) << 4) | (n & 15);   // source lane
        int e  = ((n >> 4) << 2) | (ml & 3);    // acc element index
        float s = red[0][rl][e] + red[1][rl][e] + red[2][rl][e] + red[3][rl][e];
        int m = m0 + ml;
        if (m < c) {
            int smp = lists[g * BATCH + m];
            out[(size_t)smp * MAXGS + n] = s + bias[g * MAXGS + n]; // padded n: 0+0 == 0
            out[(size_t)(BATCH + smp) * MAXGS + n] = (n < gsz) ? 1.0f : 0.0f;
        }
    }
}

extern "C" void kernel_launch(void* const* d_in, const int* in_sizes, int n_in,
                              void* d_out, int out_size, void* d_ws, size_t ws_size,
                              hipStream_t stream) {
    const float* hidden = (const float*)d_in[0];   // [8192, 8, 2048] f32
    const int*   chosen = (const int*)d_in[1];     // [8192] i32
    const float* W      = (const float*)d_in[2];   // [8, 64, 2048] f32 (zero-padded)
    const float* bias   = (const float*)d_in[3];   // [8, 64] f32 (zero-padded)
    const int*   gs     = (const int*)d_in[4];     // [8] i32
    float* out = (float*)d_out;                    // [8192*64 preds | 8192*64 valid]

    char* ws = (char*)d_ws;
    int* cnt   = (int*)ws;
    int* lists = (int*)(ws + LISTS_OFF);
    unsigned short* Wb = (unsigned short*)(ws + W_OFF);

    init_kernel<<<dim3(1024), dim3(256), 0, stream>>>(W, Wb, cnt);
    bucket_kernel<<<dim3(32), dim3(256), 0, stream>>>(chosen, cnt, lists);
    gemm_kernel<<<dim3(NGRP * TILES), dim3(256), 0, stream>>>(
        hidden, bias, gs, cnt, lists, Wb, out);
}

// Round 3
// 48.797 us; speedup vs baseline: 2.3048x; 1.2048x over previous
//
#include <hip/hip_runtime.h>
#include <hip/hip_bf16.h>

// Problem constants (from reference)
#define BATCH   8192
#define NGRP    8
#define MAXGS   64
#define DMODEL  2048
#define TILES   512       // worst-case 16-row tiles per group (BATCH/16)
#define SPLITK  8
#define KCHUNK  (DMODEL / SPLITK)   // 256

typedef __attribute__((ext_vector_type(8))) short  short8;
typedef __attribute__((ext_vector_type(4))) float  f32x4;

// ws layout:
//   [0, 512)                     int cnt[8*16]  (each counter on its own 64B line)
//   [1024, 1024 + 8*8192*4)      int lists[8][8192]
//   [W_OFF, W_OFF + 1M*2)        ushort Wb[8][64][2048]  (bf16)
#define LISTS_OFF 1024
#define W_OFF (LISTS_OFF + NGRP * BATCH * 4)
#define CNT_STRIDE 16   // ints; 64B line per counter

static __device__ __forceinline__ short bf(float f) {
    // native f32->bf16 RNE; compiler pairs these into v_cvt_pk_bf16_f32
    __hip_bfloat16 h = __float2bfloat16(f);
    return (short)__bfloat16_as_ushort(h);
}

// Phase 0: zero padded group counters + convert W (f32 -> bf16) into ws.
__global__ __launch_bounds__(256) void init_kernel(const float* __restrict__ W,
                                                   unsigned short* __restrict__ Wb,
                                                   int* __restrict__ cnt) {
    int idx = blockIdx.x * 256 + threadIdx.x;
    if (idx < NGRP * CNT_STRIDE) cnt[idx] = 0;
    int e = idx * 4;
    float4 w = *reinterpret_cast<const float4*>(W + e);
    ushort4 o;
    o.x = (unsigned short)bf(w.x); o.y = (unsigned short)bf(w.y);
    o.z = (unsigned short)bf(w.z); o.w = (unsigned short)bf(w.w);
    *reinterpret_cast<ushort4*>(Wb + e) = o;
}

// Phase 1: bucket samples by chosen group.
// LDS-aggregated: 32 LDS atomics/block + 8 global atomics/block on PADDED
// counters (previous version: 1024 device atomics serialized on ONE cache
// line — the hidden ~40+ us). List order nondeterministic; output values
// are order-independent per sample.
__global__ __launch_bounds__(256) void bucket_kernel(const int* __restrict__ chosen,
                                                     int* __restrict__ cnt,
                                                     int* __restrict__ lists) {
    __shared__ int lcnt[NGRP];
    __shared__ int lbase[NGRP];
    int tid = threadIdx.x;
    int b = blockIdx.x * 256 + tid;          // BATCH == 32*256 exactly
    int g = chosen[b];
    int lane = tid & 63;
    if (tid < NGRP) lcnt[tid] = 0;
    __syncthreads();

    int wbase = 0;
    unsigned long long mymask = 0;
    #pragma unroll
    for (int gg = 0; gg < NGRP; ++gg) {
        unsigned long long m = __ballot(g == gg);
        if (g == gg) {
            int leader = __ffsll(m) - 1;
            int wb_ = 0;
            if (lane == leader) wb_ = atomicAdd(&lcnt[gg], __popcll(m));
            wb_ = __shfl(wb_, leader);
            wbase = wb_;
            mymask = m;
        }
    }
    __syncthreads();
    if (tid < NGRP) lbase[tid] = atomicAdd(&cnt[tid * CNT_STRIDE], lcnt[tid]);
    __syncthreads();

    int pos = lbase[g] + wbase + __popcll(mymask & ((1ull << lane) - 1ull));
    lists[g * BATCH + pos] = b;
}

// Phase 2: per-group GEMM, split-K=8 inside an 8-wave (512-thread) block.
// Active blocks ~512 -> 2 blocks/CU x 8 waves = 16 waves/CU; each wave keeps
// ~4KB of A-loads queued -> aggregate per-CU in-flight >> bandwidth-delay
// product -> HBM-saturating. g = bid&7 spreads active tiles across all CUs
// (and groups align with XCDs -> per-XCD L2 caches one group's Wb).
// mfma_f32_16x16x32_bf16: A lane l: row=l&15, contiguous k per 16-lane group;
// C/D: col=l&15, row=(l>>4)*4+reg.
__global__ __launch_bounds__(512, 4) void gemm_kernel(
    const float* __restrict__ hidden,
    const float* __restrict__ bias,
    const int* __restrict__ gsizes,
    const int* __restrict__ cnt,
    const int* __restrict__ lists,
    const unsigned short* __restrict__ Wb,
    float* __restrict__ out)
{
    int bid = blockIdx.x;
    int g = bid & (NGRP - 1);
    int t = bid >> 3;
    int c = cnt[g * CNT_STRIDE];
    int m0 = t << 4;
    if (m0 >= c) return;           // empty tile: whole block exits (uniform)

    int tid  = threadIdx.x;
    int w    = tid >> 6;           // wave id 0..7 -> K chunk
    int lane = tid & 63;
    int lrow = lane & 15;
    int kg   = lane >> 4;          // 0..3

    __shared__ float red[SPLITK][64][17];   // +1 pad: conflict-light

    // A: this lane's sample row (clamped for tail; stores suppressed below)
    int mrow  = m0 + lrow;
    int msafe = mrow < c ? mrow : c - 1;
    int sample = lists[g * BATCH + msafe];
    const float* __restrict__ hrow =
        hidden + ((size_t)sample * NGRP + g) * DMODEL + w * KCHUNK + kg * 8;
    const unsigned short* __restrict__ wb =
        Wb + ((size_t)g * MAXGS + lrow) * DMODEL + w * KCHUNK + kg * 8;

    f32x4 acc[4] = {f32x4{0,0,0,0}, f32x4{0,0,0,0}, f32x4{0,0,0,0}, f32x4{0,0,0,0}};

    #pragma unroll 2
    for (int k0 = 0; k0 < KCHUNK; k0 += 32) {
        float4 a0 = *reinterpret_cast<const float4*>(hrow + k0);
        float4 a1 = *reinterpret_cast<const float4*>(hrow + k0 + 4);
        short8 af;
        af[0] = bf(a0.x); af[1] = bf(a0.y); af[2] = bf(a0.z); af[3] = bf(a0.w);
        af[4] = bf(a1.x); af[5] = bf(a1.y); af[6] = bf(a1.z); af[7] = bf(a1.w);
        short8 b0 = *reinterpret_cast<const short8*>(wb + k0);
        short8 b1 = *reinterpret_cast<const short8*>(wb + 16 * DMODEL + k0);
        short8 b2 = *reinterpret_cast<const short8*>(wb + 32 * DMODEL + k0);
        short8 b3 = *reinterpret_cast<const short8*>(wb + 48 * DMODEL + k0);
        acc[0] = __builtin_amdgcn_mfma_f32_16x16x32_bf16(af, b0, acc[0], 0, 0, 0);
        acc[1] = __builtin_amdgcn_mfma_f32_16x16x32_bf16(af, b1, acc[1], 0, 0, 0);
        acc[2] = __builtin_amdgcn_mfma_f32_16x16x32_bf16(af, b2, acc[2], 0, 0, 0);
        acc[3] = __builtin_amdgcn_mfma_f32_16x16x32_bf16(af, b3, acc[3], 0, 0, 0);
    }

    // Stash partials: red[w][lane][ti*4+r]
    #pragma unroll
    for (int ti = 0; ti < 4; ++ti)
        #pragma unroll
        for (int r = 0; r < 4; ++r)
            red[w][lane][ti * 4 + r] = acc[ti][r];

    __syncthreads();

    // Reduce over the 8 K-chunks + bias + store. 2 outputs per thread.
    int gsz = gsizes[g];
    #pragma unroll
    for (int i = 0; i < 2; ++i) {
        int o  = tid + i * 512;        // 0..1023 = (m_local, n)
        int ml = o >> 6;
        int n  = o & 63;
        int rl = ((ml >> 2) << 4) | (n & 15);   // source lane
        int e  = ((n >> 4) << 2) | (ml & 3);    // acc element index
        float s = 0.f;
        #pragma unroll
        for (int ww = 0; ww < SPLITK; ++ww) s += red[ww][rl][e];
        int m = m0 + ml;
        if (m < c) {
            int smp = lists[g * BATCH + m];
            out[(size_t)smp * MAXGS + n] = s + bias[g * MAXGS + n]; // padded n: 0+0 == 0
            out[(size_t)(BATCH + smp) * MAXGS + n] = (n < gsz) ? 1.0f : 0.0f;
        }
    }
}

extern "C" void kernel_launch(void* const* d_in, const int* in_sizes, int n_in,
                              void* d_out, int out_size, void* d_ws, size_t ws_size,
                              hipStream_t stream) {
    const float* hidden = (const float*)d_in[0];   // [8192, 8, 2048] f32
    const int*   chosen = (const int*)d_in[1];     // [8192] i32
    const float* W      = (const float*)d_in[2];   // [8, 64, 2048] f32 (zero-padded)
    const float* bias   = (const float*)d_in[3];   // [8, 64] f32 (zero-padded)
    const int*   gs     = (const int*)d_in[4];     // [8] i32
    float* out = (float*)d_out;                    // [8192*64 preds | 8192*64 valid]

    char* ws = (char*)d_ws;
    int* cnt   = (int*)ws;
    int* lists = (int*)(ws + LISTS_OFF);
    unsigned short* Wb = (unsigned short*)(ws + W_OFF);

    init_kernel<<<dim3(1024), dim3(256), 0, stream>>>(W, Wb, cnt);
    bucket_kernel<<<dim3(32), dim3(256), 0, stream>>>(chosen, cnt, lists);
    gemm_kernel<<<dim3(NGRP * TILES), dim3(512), 0, stream>>>(
        hidden, bias, gs, cnt, lists, Wb, out);
}

// Round 4
// 45.330 us; speedup vs baseline: 2.4811x; 1.0765x over previous
//
#include <hip/hip_runtime.h>
#include <hip/hip_bf16.h>

// Problem constants (from reference)
#define BATCH   8192
#define NGRP    8
#define MAXGS   64
#define DMODEL  2048
#define TILES   512       // worst-case 16-row tiles per group (BATCH/16)
#define SPLITK  4         // waves per block; each owns 1/4 of each K chunk
#define KC      512       // K elements staged per chunk
#define NCHUNK  (DMODEL / KC)   // 4

typedef __attribute__((ext_vector_type(8))) short  short8;
typedef __attribute__((ext_vector_type(4))) float  f32x4;

// ws layout:
//   [0, 512)                     int cnt[8*16]  (each counter on its own 64B line)
//   [1024, 1024 + 8*8192*4)      int lists[8][8192]
//   [W_OFF, W_OFF + 1M*2)        ushort Wb[8][64][2048]  (bf16)
#define LISTS_OFF 1024
#define W_OFF (LISTS_OFF + NGRP * BATCH * 4)
#define CNT_STRIDE 16   // ints; 64B line per counter

static __device__ __forceinline__ short bf(float f) {
    // native f32->bf16 RNE; compiler pairs these into v_cvt_pk_bf16_f32
    __hip_bfloat16 h = __float2bfloat16(f);
    return (short)__bfloat16_as_ushort(h);
}

// async global->LDS DMA, 16B per lane; dest = wave-uniform base + lane*16
static __device__ __forceinline__ void gload_lds16(const float* src, float* lds) {
    __builtin_amdgcn_global_load_lds(
        (const __attribute__((address_space(1))) unsigned int*)src,
        (__attribute__((address_space(3))) unsigned int*)lds,
        16, 0, 0);
}

// Phase 0: zero padded group counters + convert W (f32 -> bf16) into ws.
__global__ __launch_bounds__(256) void init_kernel(const float* __restrict__ W,
                                                   unsigned short* __restrict__ Wb,
                                                   int* __restrict__ cnt) {
    int idx = blockIdx.x * 256 + threadIdx.x;
    if (idx < NGRP * CNT_STRIDE) cnt[idx] = 0;
    int e = idx * 4;
    float4 w = *reinterpret_cast<const float4*>(W + e);
    ushort4 o;
    o.x = (unsigned short)bf(w.x); o.y = (unsigned short)bf(w.y);
    o.z = (unsigned short)bf(w.z); o.w = (unsigned short)bf(w.w);
    *reinterpret_cast<ushort4*>(Wb + e) = o;
}

// Phase 1: bucket samples by chosen group (LDS-aggregated atomics).
// List order nondeterministic; per-sample output values are order-independent.
__global__ __launch_bounds__(256) void bucket_kernel(const int* __restrict__ chosen,
                                                     int* __restrict__ cnt,
                                                     int* __restrict__ lists) {
    __shared__ int lcnt[NGRP];
    __shared__ int lbase[NGRP];
    int tid = threadIdx.x;
    int b = blockIdx.x * 256 + tid;          // BATCH == 32*256 exactly
    int g = chosen[b];
    int lane = tid & 63;
    if (tid < NGRP) lcnt[tid] = 0;
    __syncthreads();

    int wbase = 0;
    unsigned long long mymask = 0;
    #pragma unroll
    for (int gg = 0; gg < NGRP; ++gg) {
        unsigned long long m = __ballot(g == gg);
        if (g == gg) {
            int leader = __ffsll(m) - 1;
            int wb_ = 0;
            if (lane == leader) wb_ = atomicAdd(&lcnt[gg], __popcll(m));
            wb_ = __shfl(wb_, leader);
            wbase = wb_;
            mymask = m;
        }
    }
    __syncthreads();
    if (tid < NGRP) lbase[tid] = atomicAdd(&cnt[tid * CNT_STRIDE], lcnt[tid]);
    __syncthreads();

    int pos = lbase[g] + wbase + __popcll(mymask & ((1ull << lane) - 1ull));
    lists[g * BATCH + pos] = b;
}

// Phase 2: per-group GEMM with LDS-staged A.
// Previous direct-gather read each row in 128-256B slivers ~700cy apart ->
// ~8K interleaved row-streams -> DRAM page thrash -> 1.7 TB/s. Here each
// global_load_lds instruction pulls 1KB CONTIGUOUS from one row, and a row's
// 2KB chunk is issued back-to-back -> clean DRAM bursts.
// A staged as f32 [16][KC] with XOR swizzle (byte ^ ((row&7)<<4)) applied on
// the GLOBAL source (DMA dest must stay linear) and on the LDS read -> the
// 16-lanes-same-column ds_read_b128 16-way bank conflict becomes 2-way (free).
// Union overlays the split-K reduce buffer on A (used only after last chunk).
// mfma_f32_16x16x32_bf16: A lane l: row=l&15, contiguous k per 16-lane group;
// C/D: col=l&15, row=(l>>4)*4+reg.
__global__ __launch_bounds__(256, 3) void gemm_kernel(
    const float* __restrict__ hidden,
    const float* __restrict__ bias,
    const int* __restrict__ gsizes,
    const int* __restrict__ cnt,
    const int* __restrict__ lists,
    const unsigned short* __restrict__ Wb,
    float* __restrict__ out)
{
    int bid = blockIdx.x;
    int g = bid & (NGRP - 1);      // consecutive bids round-robin XCDs -> each
    int t = bid >> 3;              // XCD mostly sees one group's W (L2-resident)
    int c = cnt[g * CNT_STRIDE];
    int m0 = t << 4;
    if (m0 >= c) return;           // empty tile: whole block exits (uniform)

    union Smem {
        float A[16][KC];                 // 32 KB staged A chunk
        float red[SPLITK][64][17];       // 17.4 KB, used after last chunk
    };
    __shared__ Smem sm;

    int tid  = threadIdx.x;
    int w    = tid >> 6;           // wave id 0..3
    int lane = tid & 63;
    int lrow = lane & 15;
    int kg   = lane >> 4;          // 0..3

    // Each wave stages rows w*4 .. w*4+3. Gather their global row bases.
    const float* hbase[4];
    #pragma unroll
    for (int i = 0; i < 4; ++i) {
        int m  = m0 + w * 4 + i;
        int ms = m < c ? m : c - 1;          // tail: duplicate last row (harmless)
        int smp = lists[g * BATCH + ms];
        hbase[i] = hidden + ((size_t)smp * NGRP + g) * DMODEL;
    }

    f32x4 acc[4] = {f32x4{0,0,0,0}, f32x4{0,0,0,0}, f32x4{0,0,0,0}, f32x4{0,0,0,0}};
    int swr = (lrow & 7) << 4;     // read-side XOR swizzle for this lane's row

    for (int ch = 0; ch < NCHUNK; ++ch) {
        // ---- stage: 4 rows x 2KB per wave, 1KB contiguous per instruction ----
        #pragma unroll
        for (int i = 0; i < 4; ++i) {
            int r  = w * 4 + i;
            int sw = (r & 7) << 4;
            const float* src = hbase[i] + ch * KC;
            #pragma unroll
            for (int h = 0; h < 2; ++h) {
                // LDS[r][x] must hold global[row][x ^ sw]; x = h*1024 + lane*16
                int lb = (h * 1024 + lane * 16) ^ sw;   // bytes; XOR stays in-row
                gload_lds16(src + (lb >> 2), &sm.A[r][h * 256]);
            }
        }
        __syncthreads();   // compiler drains vmcnt(0) before barrier — wanted here

        // ---- compute: wave w owns k in [w*128, w*128+128) of this chunk ----
        #pragma unroll
        for (int kk = 0; kk < 4; ++kk) {
            int xb = w * 512 + kk * 128 + kg * 32;      // byte offset within row
            const char* arow = (const char*)&sm.A[lrow][0];
            f32x4 alo = *reinterpret_cast<const f32x4*>(arow + ((xb) ^ swr));
            f32x4 ahi = *reinterpret_cast<const f32x4*>(arow + ((xb + 16) ^ swr));
            short8 af;
            af[0] = bf(alo[0]); af[1] = bf(alo[1]); af[2] = bf(alo[2]); af[3] = bf(alo[3]);
            af[4] = bf(ahi[0]); af[5] = bf(ahi[1]); af[6] = bf(ahi[2]); af[7] = bf(ahi[3]);

            int kglob = ch * KC + w * 128 + kk * 32 + kg * 8;
            const unsigned short* wbp = Wb + ((size_t)g * MAXGS + lrow) * DMODEL + kglob;
            short8 b0 = *reinterpret_cast<const short8*>(wbp);
            short8 b1 = *reinterpret_cast<const short8*>(wbp + 16 * DMODEL);
            short8 b2 = *reinterpret_cast<const short8*>(wbp + 32 * DMODEL);
            short8 b3 = *reinterpret_cast<const short8*>(wbp + 48 * DMODEL);
            acc[0] = __builtin_amdgcn_mfma_f32_16x16x32_bf16(af, b0, acc[0], 0, 0, 0);
            acc[1] = __builtin_amdgcn_mfma_f32_16x16x32_bf16(af, b1, acc[1], 0, 0, 0);
            acc[2] = __builtin_amdgcn_mfma_f32_16x16x32_bf16(af, b2, acc[2], 0, 0, 0);
            acc[3] = __builtin_amdgcn_mfma_f32_16x16x32_bf16(af, b3, acc[3], 0, 0, 0);
        }
        __syncthreads();   // all reads done before next stage / red overlay
    }

    // ---- split-K reduce (red overlays A; all A reads are behind the barrier) ----
    #pragma unroll
    for (int ti = 0; ti < 4; ++ti)
        #pragma unroll
        for (int r = 0; r < 4; ++r)
            sm.red[w][lane][ti * 4 + r] = acc[ti][r];
    __syncthreads();

    int gsz = gsizes[g];
    #pragma unroll
    for (int i = 0; i < 4; ++i) {
        int o  = tid + i * 256;        // 0..1023 = (m_local, n)
        int ml = o >> 6;
        int n  = o & 63;
        int rl = ((ml >> 2) << 4) | (n & 15);   // source lane
        int e  = ((n >> 4) << 2) | (ml & 3);    // acc element index
        float s = sm.red[0][rl][e] + sm.red[1][rl][e]
                + sm.red[2][rl][e] + sm.red[3][rl][e];
        int m = m0 + ml;
        if (m < c) {
            int smp = lists[g * BATCH + m];
            out[(size_t)smp * MAXGS + n] = s + bias[g * MAXGS + n]; // padded n: 0+0 == 0
            out[(size_t)(BATCH + smp) * MAXGS + n] = (n < gsz) ? 1.0f : 0.0f;
        }
    }
}

extern "C" void kernel_launch(void* const* d_in, const int* in_sizes, int n_in,
                              void* d_out, int out_size, void* d_ws, size_t ws_size,
                              hipStream_t stream) {
    const float* hidden = (const float*)d_in[0];   // [8192, 8, 2048] f32
    const int*   chosen = (const int*)d_in[1];     // [8192] i32
    const float* W      = (const float*)d_in[2];   // [8, 64, 2048] f32 (zero-padded)
    const float* bias   = (const float*)d_in[3];   // [8, 64] f32 (zero-padded)
    const int*   gs     = (const int*)d_in[4];     // [8] i32
    float* out = (float*)d_out;                    // [8192*64 preds | 8192*64 valid]

    char* ws = (char*)d_ws;
    int* cnt   = (int*)ws;
    int* lists = (int*)(ws + LISTS_OFF);
    unsigned short* Wb = (unsigned short*)(ws + W_OFF);

    init_kernel<<<dim3(1024), dim3(256), 0, stream>>>(W, Wb, cnt);
    bucket_kernel<<<dim3(32), dim3(256), 0, stream>>>(chosen, cnt, lists);
    gemm_kernel<<<dim3(NGRP * TILES), dim3(256), 0, stream>>>(
        hidden, bias, gs, cnt, lists, Wb, out);
}